// Round 6
// baseline (578.276 us; speedup 1.0000x reference)
//
#include <hip/hip_runtime.h>

#define BB 1024
#define TB 512
#define FB 64
#define NH1 32
#define NH2 16
#define ND1 16
#define ND2 8

// Wavefront-scope fence: runtime-free, but a hard compiler barrier against
// LDS motion across the masked-publish -> cross-lane-read handoff.
#define WAVE_FENCE() __builtin_amdgcn_fence(__ATOMIC_ACQ_REL, "wavefront")

__device__ __forceinline__ float tanh_fast(float v) {
    // tanh(x) = 1 - 2/(e^{2x}+1); exp inf/0 limits give exactly +-1.
    float e = __expf(2.0f * v);
    return fmaf(-2.0f, __builtin_amdgcn_rcpf(e + 1.0f), 1.0f);
}

// TWO batches per wave: 512 blocks x 64 threads = 2 waves/CU. Each wave
// interleaves two independent recurrences so one chain's DS latency
// (h1 publish -> read ~130cyc, shfl ~120cyc) is hidden by the other's
// issue. Weight registers are lane-indexed -> shared by both batches.
__global__ __attribute__((amdgpu_flat_work_group_size(64, 64)))
           __attribute__((amdgpu_waves_per_eu(1, 1)))
void rnn_fused_kernel(
    const float* __restrict__ x,
    const float* __restrict__ Wx1, const float* __restrict__ Wh1, const float* __restrict__ b1,
    const float* __restrict__ Wx2, const float* __restrict__ Wh2, const float* __restrict__ b2,
    const float* __restrict__ W3,  const float* __restrict__ b3,
    const float* __restrict__ W4,  const float* __restrict__ b4,
    const float* __restrict__ Wo,  const float* __restrict__ bo,
    float* __restrict__ out)
{
    __shared__ __align__(16) float xsA[2][FB], xsB[2][FB];  // x staging (dbuf)
    __shared__ __align__(16) float h1A[NH1],  h1B[NH1];     // h1 broadcast
    __shared__ __align__(16) float h2A[NH2],  h2B[NH2];     // h2 state
    __shared__ __align__(16) float ysA[ND1],  ysB[ND1];     // head temp

    const int lane = threadIdx.x;   // 0..63
    const int h = lane & 31;        // layer-1 output unit
    const int p = lane >> 5;        // half (0,1): f/j split for layer 1
    const int g = lane & 15;        // layer-2 output unit
    const int q = lane >> 4;        // quarter (0..3): input split for layer 2
    const int bA = blockIdx.x * 2;
    const int bB = bA + 1;

    // ---- weights as NAMED float4 registers (shared across both batches) ----
    auto w1 = [&](int i) { return Wx1[(32 * p + i) * NH1 + h]; };
    auto r1 = [&](int i) { return Wh1[(16 * p + i) * NH1 + h]; };
    auto w2 = [&](int i) { return Wx2[(8 * q + i) * NH2 + g]; };
    auto r2 = [&](int i) { return Wh2[(4 * q + i) * NH2 + g]; };
    const float4 wxa = make_float4(w1(0),  w1(1),  w1(2),  w1(3));
    const float4 wxb = make_float4(w1(4),  w1(5),  w1(6),  w1(7));
    const float4 wxc = make_float4(w1(8),  w1(9),  w1(10), w1(11));
    const float4 wxd = make_float4(w1(12), w1(13), w1(14), w1(15));
    const float4 wxe = make_float4(w1(16), w1(17), w1(18), w1(19));
    const float4 wxf = make_float4(w1(20), w1(21), w1(22), w1(23));
    const float4 wxg = make_float4(w1(24), w1(25), w1(26), w1(27));
    const float4 wxh = make_float4(w1(28), w1(29), w1(30), w1(31));
    const float4 wha = make_float4(r1(0),  r1(1),  r1(2),  r1(3));
    const float4 whb = make_float4(r1(4),  r1(5),  r1(6),  r1(7));
    const float4 whc = make_float4(r1(8),  r1(9),  r1(10), r1(11));
    const float4 whd = make_float4(r1(12), r1(13), r1(14), r1(15));
    const float4 x2a = make_float4(w2(0), w2(1), w2(2), w2(3));
    const float4 x2b = make_float4(w2(4), w2(5), w2(6), w2(7));
    const float4 h2w = make_float4(r2(0), r2(1), r2(2), r2(3));
    const float b1v = (p == 0) ? b1[h] : 0.0f;
    const float b2v = (q == 0) ? b2[g] : 0.0f;

    // ---- init state ----
    if (lane < NH1) { h1A[lane] = 0.0f; h1B[lane] = 0.0f; }
    if (lane < NH2) { h2A[lane] = 0.0f; h2B[lane] = 0.0f; }

    // ---- x prefetch queues: 4 named scalars per batch ----
    const float* xpA = x + (size_t)bA * TB * FB + lane;
    const float* xpB = x + (size_t)bB * TB * FB + lane;
    float qa0 = xpA[0 * FB], qa1 = xpA[1 * FB], qa2 = xpA[2 * FB], qa3 = xpA[3 * FB];
    float qb0 = xpB[0 * FB], qb1 = xpB[1 * FB], qb2 = xpB[2 * FB], qb3 = xpB[3 * FB];
    xsA[0][lane] = qa0;
    xsB[0][lane] = qb0;
    __syncthreads();  // once, before the loop

// One timestep for one batch. All h1s/h2s reads happen BEFORE the fence +
// masked publishes (values = h1_{t-1}, h2_{t-2}; in-order DS queue returns
// pre-publish data; fence stops compiler motion). h1 publish goes BEFORE
// the layer-2 block so the next step's h1 read doesn't queue behind
// layer-2's two shfls.
#define STEP1(T, SLOT, XS, H1S, H2S, XPTR, QSTAGE, QREFILL)                    \
    {                                                                          \
        const int t_ = (T);                                                    \
        int tn_ = t_ + 4; tn_ = (tn_ < TB) ? tn_ : (TB - 1);                   \
        const float xnew_ = XPTR[tn_ * FB];                                    \
        XS[(SLOT) ^ 1][lane] = QSTAGE;                                         \
        float4 hva = *(const float4*)&H1S[16 * p + 0];                         \
        float4 hvb = *(const float4*)&H1S[16 * p + 4];                         \
        float4 hvc = *(const float4*)&H1S[16 * p + 8];                         \
        float4 hvd = *(const float4*)&H1S[16 * p + 12];                        \
        float4 u0 = *(const float4*)&H1S[8 * q + 0];  /* h1_{t-1} for L2 */    \
        float4 u1 = *(const float4*)&H1S[8 * q + 4];                           \
        float4 hw = *(const float4*)&H2S[4 * q];      /* h2_{t-2} for L2 */    \
        const float4* xv = (const float4*)&XS[SLOT][32 * p];                   \
        float a0 = b1v, a1 = 0.0f, a2 = 0.0f, a3 = 0.0f;                       \
        float4 v_;                                                             \
        v_ = xv[0]; a0 = fmaf(v_.x, wxa.x, a0); a1 = fmaf(v_.y, wxa.y, a1);    \
                    a2 = fmaf(v_.z, wxa.z, a2); a3 = fmaf(v_.w, wxa.w, a3);    \
        v_ = xv[1]; a0 = fmaf(v_.x, wxb.x, a0); a1 = fmaf(v_.y, wxb.y, a1);    \
                    a2 = fmaf(v_.z, wxb.z, a2); a3 = fmaf(v_.w, wxb.w, a3);    \
        v_ = xv[2]; a0 = fmaf(v_.x, wxc.x, a0); a1 = fmaf(v_.y, wxc.y, a1);    \
                    a2 = fmaf(v_.z, wxc.z, a2); a3 = fmaf(v_.w, wxc.w, a3);    \
        v_ = xv[3]; a0 = fmaf(v_.x, wxd.x, a0); a1 = fmaf(v_.y, wxd.y, a1);    \
                    a2 = fmaf(v_.z, wxd.z, a2); a3 = fmaf(v_.w, wxd.w, a3);    \
        v_ = xv[4]; a0 = fmaf(v_.x, wxe.x, a0); a1 = fmaf(v_.y, wxe.y, a1);    \
                    a2 = fmaf(v_.z, wxe.z, a2); a3 = fmaf(v_.w, wxe.w, a3);    \
        v_ = xv[5]; a0 = fmaf(v_.x, wxf.x, a0); a1 = fmaf(v_.y, wxf.y, a1);    \
                    a2 = fmaf(v_.z, wxf.z, a2); a3 = fmaf(v_.w, wxf.w, a3);    \
        v_ = xv[6]; a0 = fmaf(v_.x, wxg.x, a0); a1 = fmaf(v_.y, wxg.y, a1);    \
                    a2 = fmaf(v_.z, wxg.z, a2); a3 = fmaf(v_.w, wxg.w, a3);    \
        v_ = xv[7]; a0 = fmaf(v_.x, wxh.x, a0); a1 = fmaf(v_.y, wxh.y, a1);    \
                    a2 = fmaf(v_.z, wxh.z, a2); a3 = fmaf(v_.w, wxh.w, a3);    \
        a0 = fmaf(hva.x, wha.x, a0); a1 = fmaf(hva.y, wha.y, a1);              \
        a2 = fmaf(hva.z, wha.z, a2); a3 = fmaf(hva.w, wha.w, a3);              \
        a0 = fmaf(hvb.x, whb.x, a0); a1 = fmaf(hvb.y, whb.y, a1);              \
        a2 = fmaf(hvb.z, whb.z, a2); a3 = fmaf(hvb.w, whb.w, a3);              \
        a0 = fmaf(hvc.x, whc.x, a0); a1 = fmaf(hvc.y, whc.y, a1);              \
        a2 = fmaf(hvc.z, whc.z, a2); a3 = fmaf(hvc.w, whc.w, a3);              \
        a0 = fmaf(hvd.x, whd.x, a0); a1 = fmaf(hvd.y, whd.y, a1);              \
        a2 = fmaf(hvd.z, whd.z, a2); a3 = fmaf(hvd.w, whd.w, a3);              \
        float acc = (a0 + a1) + (a2 + a3);                                     \
        acc += __shfl_xor(acc, 32, 64);                                        \
        float h1new = tanh_fast(acc);                                          \
        WAVE_FENCE(); /* all reads of this batch's LDS are above */            \
        if (p == 0) H1S[h] = h1new;  /* publish EARLY: before L2's shfls */    \
        if (t_ > 0) {  /* layer 2, one step behind: h2_{t-1} */                \
            float c0 = b2v, c1 = 0.0f;                                         \
            c0 = fmaf(u0.x, x2a.x, c0); c1 = fmaf(u0.y, x2a.y, c1);            \
            c0 = fmaf(u0.z, x2a.z, c0); c1 = fmaf(u0.w, x2a.w, c1);            \
            c0 = fmaf(u1.x, x2b.x, c0); c1 = fmaf(u1.y, x2b.y, c1);            \
            c0 = fmaf(u1.z, x2b.z, c0); c1 = fmaf(u1.w, x2b.w, c1);            \
            c0 = fmaf(hw.x, h2w.x, c0); c1 = fmaf(hw.y, h2w.y, c1);            \
            c0 = fmaf(hw.z, h2w.z, c0); c1 = fmaf(hw.w, h2w.w, c1);            \
            float cc = c0 + c1;                                                \
            cc += __shfl_xor(cc, 16, 64);                                      \
            cc += __shfl_xor(cc, 32, 64);                                      \
            float h2new = tanh_fast(cc);                                       \
            if (lane < NH2) H2S[lane] = h2new;                                 \
        }                                                                      \
        QREFILL = xnew_;                                                       \
    }

// Interleave the two batches: B's issue fills A's DS-latency stalls.
#define PHASE(T, SLOT, QSA, QRA, QSB, QRB)                                     \
    {                                                                          \
        WAVE_FENCE(); /* step boundary: no LDS motion across */                \
        STEP1(T, SLOT, xsA, h1A, h2A, xpA, QSA, QRA)                           \
        STEP1(T, SLOT, xsB, h1B, h2B, xpB, QSB, QRB)                           \
    }

    for (int tb = 0; tb < TB; tb += 4) {
        PHASE(tb + 0, 0, qa1, qa0, qb1, qb0);
        PHASE(tb + 1, 1, qa2, qa1, qb2, qb1);
        PHASE(tb + 2, 0, qa3, qa2, qb3, qb2);
        PHASE(tb + 3, 1, qa0, qa3, qb0, qb3);
    }
#undef PHASE
#undef STEP1

    WAVE_FENCE();

// Final layer-2 step (h2_{T-1}) + dense head for one batch.
#define TAIL(H1S, H2S, YS, BOUT)                                               \
    {                                                                          \
        float4 u0 = *(const float4*)&H1S[8 * q + 0];                           \
        float4 u1 = *(const float4*)&H1S[8 * q + 4];                           \
        float4 hw = *(const float4*)&H2S[4 * q];                               \
        float c0 = b2v, c1 = 0.0f;                                             \
        c0 = fmaf(u0.x, x2a.x, c0); c1 = fmaf(u0.y, x2a.y, c1);                \
        c0 = fmaf(u0.z, x2a.z, c0); c1 = fmaf(u0.w, x2a.w, c1);                \
        c0 = fmaf(u1.x, x2b.x, c0); c1 = fmaf(u1.y, x2b.y, c1);                \
        c0 = fmaf(u1.z, x2b.z, c0); c1 = fmaf(u1.w, x2b.w, c1);                \
        c0 = fmaf(hw.x, h2w.x, c0); c1 = fmaf(hw.y, h2w.y, c1);                \
        c0 = fmaf(hw.z, h2w.z, c0); c1 = fmaf(hw.w, h2w.w, c1);                \
        float cc = c0 + c1;                                                    \
        cc += __shfl_xor(cc, 16, 64);                                          \
        cc += __shfl_xor(cc, 32, 64);                                          \
        float h2fin = tanh_fast(cc);                                           \
        WAVE_FENCE();                                                          \
        if (lane < NH2) H2S[lane] = h2fin;                                     \
        WAVE_FENCE();                                                          \
        float a3h = b3[g];                                                     \
        _Pragma("unroll")                                                      \
        for (int j = 0; j < 16; ++j) a3h = fmaf(H2S[j], W3[j * ND1 + g], a3h); \
        float y1 = fmaxf(a3h, 0.0f);                                           \
        WAVE_FENCE();                                                          \
        if (lane < ND1) YS[lane] = y1;                                         \
        WAVE_FENCE();                                                          \
        const int e_ = lane & 7;                                               \
        float a4 = b4[e_];                                                     \
        _Pragma("unroll")                                                      \
        for (int j = 0; j < 16; ++j) a4 = fmaf(YS[j], W4[j * ND2 + e_], a4);   \
        float yo = a4 * Wo[e_];                                                \
        yo += __shfl_xor(yo, 1, 64);                                           \
        yo += __shfl_xor(yo, 2, 64);                                           \
        yo += __shfl_xor(yo, 4, 64);                                           \
        if (lane == 0) out[BOUT] = yo + bo[0];                                 \
    }

    TAIL(h1A, h2A, ysA, bA)
    TAIL(h1B, h2B, ysB, bB)
#undef TAIL
}

extern "C" void kernel_launch(void* const* d_in, const int* in_sizes, int n_in,
                              void* d_out, int out_size, void* d_ws, size_t ws_size,
                              hipStream_t stream) {
    const float* x   = (const float*)d_in[0];
    const float* Wx1 = (const float*)d_in[1];
    const float* Wh1 = (const float*)d_in[2];
    const float* b1  = (const float*)d_in[3];
    const float* Wx2 = (const float*)d_in[4];
    const float* Wh2 = (const float*)d_in[5];
    const float* b2  = (const float*)d_in[6];
    const float* W3  = (const float*)d_in[7];
    const float* b3  = (const float*)d_in[8];
    const float* W4  = (const float*)d_in[9];
    const float* b4  = (const float*)d_in[10];
    const float* Wo  = (const float*)d_in[11];
    const float* bo  = (const float*)d_in[12];
    float* out = (float*)d_out;

    rnn_fused_kernel<<<dim3(BB / 2), dim3(64), 0, stream>>>(
        x, Wx1, Wh1, b1, Wx2, Wh2, b2, W3, b3, W4, b4, Wo, bo, out);
}

// Round 7
// 365.168 us; speedup vs baseline: 1.5836x; 1.5836x over previous
//
#include <hip/hip_runtime.h>

#define BB 1024
#define TB 512
#define FB 64
#define NH1 32
#define NH2 16
#define ND1 16
#define ND2 8

typedef float v2f __attribute__((ext_vector_type(2)));

// Wavefront-scope fence: runtime-free compiler barrier for LDS motion.
#define WAVE_FENCE() __builtin_amdgcn_fence(__ATOMIC_ACQ_REL, "wavefront")

__device__ __forceinline__ v2f fma2(v2f a, v2f b, v2f c) {
    return __builtin_elementwise_fma(a, b, c);   // -> v_pk_fma_f32
}

__device__ __forceinline__ float tanh_fast(float v) {
    // tanh(x) = 1 - 2/(e^{2x}+1); exp inf/0 limits give exactly +-1.
    float e = __expf(2.0f * v);
    return fmaf(-2.0f, __builtin_amdgcn_rcpf(e + 1.0f), 1.0f);
}

// TWO batches per wave, split across half-waves IN THE LANES (same
// instructions, different data) — round 6 proved sequential-code batch
// pairing just doubles issue. Shfl-free: every lane computes the FULL
// recurrence dot for its (batch, unit); h1/h2 state round-trips through
// LDS as broadcast b128 reads (2 unique addrs/inst = free, m136).
__global__ __attribute__((amdgpu_flat_work_group_size(64, 64)))
           __attribute__((amdgpu_waves_per_eu(1, 1)))
void rnn_fused_kernel(
    const float* __restrict__ x,
    const float* __restrict__ Wx1, const float* __restrict__ Wh1, const float* __restrict__ b1,
    const float* __restrict__ Wx2, const float* __restrict__ Wh2, const float* __restrict__ b2,
    const float* __restrict__ W3,  const float* __restrict__ b3,
    const float* __restrict__ W4,  const float* __restrict__ b4,
    const float* __restrict__ Wo,  const float* __restrict__ bo,
    float* __restrict__ out)
{
    __shared__ __align__(16) float xs[2][2][FB];   // [slot][bsel][f] x staging
    __shared__ __align__(16) float h1AB[2 * NH1];  // [bsel*32 + u]
    __shared__ __align__(16) float h2AB[2 * NH2];  // [bsel*16 + g]
    __shared__ __align__(16) float ysAB[2 * ND1];  // head temp

    const int lane = threadIdx.x;   // 0..63
    const int u    = lane & 31;     // layer-1 unit
    const int bsel = lane >> 5;     // batch half: 0=A, 1=B
    const int g    = lane & 15;     // layer-2 unit (lanes 16..31 redundant)
    const int e    = lane & 7;      // head unit
    const int b0   = blockIdx.x * 2;

    // ---- weights: packed v2f register arrays (const-indexed, fully unrolled)
    v2f wx1r[32], wh1r[16], wx2r[16], wh2r[8];
#pragma unroll
    for (int i = 0; i < 32; ++i)
        wx1r[i] = (v2f){Wx1[(2*i)*NH1 + u], Wx1[(2*i+1)*NH1 + u]};
#pragma unroll
    for (int i = 0; i < 16; ++i)
        wh1r[i] = (v2f){Wh1[(2*i)*NH1 + u], Wh1[(2*i+1)*NH1 + u]};
#pragma unroll
    for (int i = 0; i < 16; ++i)
        wx2r[i] = (v2f){Wx2[(2*i)*NH2 + g], Wx2[(2*i+1)*NH2 + g]};
#pragma unroll
    for (int i = 0; i < 8; ++i)
        wh2r[i] = (v2f){Wh2[(2*i)*NH2 + g], Wh2[(2*i+1)*NH2 + g]};
    const float b1v = b1[u];
    const float b2v = b2[g];

    // head weights (preloaded once)
    float w3r[16], w4r[16];
#pragma unroll
    for (int j = 0; j < 16; ++j) w3r[j] = W3[j * ND1 + g];
#pragma unroll
    for (int j = 0; j < 16; ++j) w4r[j] = W4[j * ND2 + e];
    const float wor = Wo[e];
    const float b3v = b3[g], b4v = b4[e], bov = bo[0];

    // ---- init state ----
    h1AB[lane] = 0.0f;
    if (lane < 2 * NH2) h2AB[lane] = 0.0f;

    // ---- x prefetch queue: 4 named v2f (each lane covers 2 features of its
    // own batch; lanes 0-31 = batch A f[0..64), lanes 32-63 = batch B) ----
    const float* xlane = x + (size_t)(b0 + bsel) * TB * FB + 2 * u;
    v2f q0 = *(const v2f*)(xlane + 0 * FB);
    v2f q1 = *(const v2f*)(xlane + 1 * FB);
    v2f q2 = *(const v2f*)(xlane + 2 * FB);
    v2f q3 = *(const v2f*)(xlane + 3 * FB);
    *(v2f*)&xs[0][bsel][2 * u] = q0;
    __syncthreads();  // once, before the loop

// One timestep, both batches (lane-split). All LDS reads precede the fence +
// publishes. L2 runs one step behind using the h1/h2 REGISTERS read this
// step (h1_{t-1}, h2_{t-2}) — no LDS reads after the publish fence.
#define STEP(T, SLOT, QSTAGE, QREFILL)                                         \
    {                                                                          \
        WAVE_FENCE(); /* step boundary: no LDS motion across */                \
        const int t_ = (T);                                                    \
        int tn_ = t_ + 4; tn_ = (tn_ < TB) ? tn_ : (TB - 1);                   \
        const v2f xnew_ = *(const v2f*)(xlane + tn_ * FB);                     \
        /* ---- issue all DS reads up front (latency pipelines) ---- */        \
        const float4* h1p = (const float4*)&h1AB[bsel * NH1];                  \
        v2f h1r[16];                                                           \
        _Pragma("unroll")                                                      \
        for (int k = 0; k < 8; ++k) {                                          \
            float4 f = h1p[k];                                                 \
            h1r[2*k]   = (v2f){f.x, f.y};                                      \
            h1r[2*k+1] = (v2f){f.z, f.w};                                      \
        }                                                                      \
        const float4* h2p = (const float4*)&h2AB[bsel * NH2];                  \
        v2f h2r[8];                                                            \
        _Pragma("unroll")                                                      \
        for (int k = 0; k < 4; ++k) {                                          \
            float4 f = h2p[k];                                                 \
            h2r[2*k]   = (v2f){f.x, f.y};                                      \
            h2r[2*k+1] = (v2f){f.z, f.w};                                      \
        }                                                                      \
        const float4* xvp = (const float4*)&xs[SLOT][bsel][0];                 \
        float4 xv[16];                                                         \
        _Pragma("unroll")                                                      \
        for (int k = 0; k < 16; ++k) xv[k] = xvp[k];                           \
        *(v2f*)&xs[(SLOT) ^ 1][bsel][2 * u] = QSTAGE; /* stage x_{t+1} */      \
        /* ---- xp1 (full 64-dot) + rec1 (full 32-dot), packed fp32 ---- */    \
        v2f a0 = (v2f){b1v, 0.0f}, a1 = (v2f){0.0f, 0.0f};                     \
        v2f a2 = (v2f){0.0f, 0.0f}, a3 = (v2f){0.0f, 0.0f};                    \
        _Pragma("unroll")                                                      \
        for (int k = 0; k < 16; k += 2) {                                      \
            float4 v = xv[k], w = xv[k+1];                                     \
            a0 = fma2((v2f){v.x, v.y}, wx1r[2*k],   a0);                       \
            a1 = fma2((v2f){v.z, v.w}, wx1r[2*k+1], a1);                       \
            a2 = fma2((v2f){w.x, w.y}, wx1r[2*k+2], a2);                       \
            a3 = fma2((v2f){w.z, w.w}, wx1r[2*k+3], a3);                       \
        }                                                                      \
        _Pragma("unroll")                                                      \
        for (int i = 0; i < 16; i += 4) {                                      \
            a0 = fma2(h1r[i+0], wh1r[i+0], a0);                                \
            a1 = fma2(h1r[i+1], wh1r[i+1], a1);                                \
            a2 = fma2(h1r[i+2], wh1r[i+2], a2);                                \
            a3 = fma2(h1r[i+3], wh1r[i+3], a3);                                \
        }                                                                      \
        v2f s_ = (a0 + a1) + (a2 + a3);                                        \
        float h1new = tanh_fast(s_.x + s_.y);                                  \
        WAVE_FENCE(); /* all LDS reads are above */                            \
        h1AB[lane] = h1new;  /* publish h1_t: one unmasked write */            \
        if (t_ > 0) {  /* layer 2, one behind: h2_{t-1} from regs only */      \
            v2f c0 = (v2f){b2v, 0.0f}, c1 = (v2f){0.0f, 0.0f};                 \
            _Pragma("unroll")                                                  \
            for (int i = 0; i < 16; i += 2) {                                  \
                c0 = fma2(h1r[i],   wx2r[i],   c0);                            \
                c1 = fma2(h1r[i+1], wx2r[i+1], c1);                            \
            }                                                                  \
            _Pragma("unroll")                                                  \
            for (int i = 0; i < 8; i += 2) {                                   \
                c0 = fma2(h2r[i],   wh2r[i],   c0);                            \
                c1 = fma2(h2r[i+1], wh2r[i+1], c1);                            \
            }                                                                  \
            v2f cs = c0 + c1;                                                  \
            float h2new = tanh_fast(cs.x + cs.y);                              \
            if ((lane & 31) < NH2) h2AB[bsel * NH2 + g] = h2new;               \
        }                                                                      \
        QREFILL = xnew_;                                                       \
    }

    for (int tb = 0; tb < TB; tb += 4) {
        STEP(tb + 0, 0, q1, q0)
        STEP(tb + 1, 1, q2, q1)
        STEP(tb + 2, 0, q3, q2)
        STEP(tb + 3, 1, q0, q3)
    }
#undef STEP

    WAVE_FENCE();

    // ---- epilogue: final L2 step (h2_{T-1} from h1_{T-1}) ----
    {
        const float4* h1p = (const float4*)&h1AB[bsel * NH1];
        v2f h1r[16];
#pragma unroll
        for (int k = 0; k < 8; ++k) {
            float4 f = h1p[k];
            h1r[2*k]   = (v2f){f.x, f.y};
            h1r[2*k+1] = (v2f){f.z, f.w};
        }
        const float4* h2p = (const float4*)&h2AB[bsel * NH2];
        v2f h2r[8];
#pragma unroll
        for (int k = 0; k < 4; ++k) {
            float4 f = h2p[k];
            h2r[2*k]   = (v2f){f.x, f.y};
            h2r[2*k+1] = (v2f){f.z, f.w};
        }
        v2f c0 = (v2f){b2v, 0.0f}, c1 = (v2f){0.0f, 0.0f};
#pragma unroll
        for (int i = 0; i < 16; i += 2) {
            c0 = fma2(h1r[i],   wx2r[i],   c0);
            c1 = fma2(h1r[i+1], wx2r[i+1], c1);
        }
#pragma unroll
        for (int i = 0; i < 8; i += 2) {
            c0 = fma2(h2r[i],   wh2r[i],   c0);
            c1 = fma2(h2r[i+1], wh2r[i+1], c1);
        }
        v2f cs = c0 + c1;
        float h2fin = tanh_fast(cs.x + cs.y);
        WAVE_FENCE();
        if ((lane & 31) < NH2) h2AB[bsel * NH2 + g] = h2fin;
        WAVE_FENCE();
    }

    // ---- dense head (both batches in parallel via bsel) ----
    {
        float a3h = b3v;
#pragma unroll
        for (int j = 0; j < 16; ++j) a3h = fmaf(h2AB[bsel * NH2 + j], w3r[j], a3h);
        float y1 = fmaxf(a3h, 0.0f);
        WAVE_FENCE();
        if ((lane & 31) < ND1) ysAB[bsel * ND1 + g] = y1;
        WAVE_FENCE();

        float a4 = b4v;
#pragma unroll
        for (int j = 0; j < 16; ++j) a4 = fmaf(ysAB[bsel * ND1 + j], w4r[j], a4);

        float yo = a4 * wor;           // e = lane&7; reduce within 8-lane group
        yo += __shfl_xor(yo, 1, 64);
        yo += __shfl_xor(yo, 2, 64);
        yo += __shfl_xor(yo, 4, 64);
        if (lane == 0)  out[b0 + 0] = yo + bov;
        if (lane == 32) out[b0 + 1] = yo + bov;
    }
}

extern "C" void kernel_launch(void* const* d_in, const int* in_sizes, int n_in,
                              void* d_out, int out_size, void* d_ws, size_t ws_size,
                              hipStream_t stream) {
    const float* x   = (const float*)d_in[0];
    const float* Wx1 = (const float*)d_in[1];
    const float* Wh1 = (const float*)d_in[2];
    const float* b1  = (const float*)d_in[3];
    const float* Wx2 = (const float*)d_in[4];
    const float* Wh2 = (const float*)d_in[5];
    const float* b2  = (const float*)d_in[6];
    const float* W3  = (const float*)d_in[7];
    const float* b3  = (const float*)d_in[8];
    const float* W4  = (const float*)d_in[9];
    const float* b4  = (const float*)d_in[10];
    const float* Wo  = (const float*)d_in[11];
    const float* bo  = (const float*)d_in[12];
    float* out = (float*)d_out;

    rnn_fused_kernel<<<dim3(BB / 2), dim3(64), 0, stream>>>(
        x, Wx1, Wh1, b1, Wx2, Wh2, b2, W3, b3, W4, b4, Wo, bo, out);
}